// Round 3
// baseline (563.523 us; speedup 1.0000x reference)
//
#include <hip/hip_runtime.h>

#define BB 4
#define VV 256
#define HH 128
#define NROWS (BB*VV)            // 1024
#define NE_CNT (BB*VV*VV)        // 262144
#define EPSV 1e-5f

typedef float4 f4;
typedef short bf16x8 __attribute__((ext_vector_type(8)));   // 8 bf16 = 4 VGPR
typedef float f32x4 __attribute__((ext_vector_type(4)));    // MFMA C/D

__device__ __forceinline__ float sigm(float x) {
    return 1.f / (1.f + __expf(-x));
}

__device__ __forceinline__ unsigned short bf16_rne(float x) {
    union { float f; unsigned u; } v; v.f = x;
    unsigned r = v.u + 0x7fffu + ((v.u >> 16) & 1u);
    return (unsigned short)(r >> 16);
}
__device__ __forceinline__ float bf16_to_f(unsigned short h) {
    union { unsigned u; float f; } v; v.u = ((unsigned)h) << 16;
    return v.f;
}
__device__ __forceinline__ void split_bf16(float x, short& hi, short& lo) {
    unsigned short h = bf16_rne(x);
    hi = (short)h;
    lo = (short)bf16_rne(x - bf16_to_f(h));
}

__device__ __forceinline__ f32x4 mfma16(bf16x8 a, bf16x8 b, f32x4 c) {
    return __builtin_amdgcn_mfma_f32_16x16x32_bf16(a, b, c, 0, 0, 0);
}

// ---------------------------------------------------------------------------
// K0: convert the 5 weight matrices (WU,WV,WA,WB,WC; each [n=128][k=128],
// row-major = exactly MFMA B-operand k-contiguous order) into fragment-linear
// hi/lo bf16 arrays: WFH/WFL[((mat*32 + nt*4+kt)*64 + lane)*8 + j].
// B-frag layout (16x16x32): lane = n_local + 16*quad, holds k = quad*8 + j.
// ---------------------------------------------------------------------------
__global__ __launch_bounds__(256) void k_prep(
    const float* __restrict__ W0, const float* __restrict__ W1,
    const float* __restrict__ W2, const float* __restrict__ W3,
    const float* __restrict__ W4,
    short* __restrict__ WFH, short* __restrict__ WFL)
{
    int g = blockIdx.x*256 + threadIdx.x;    // 5*2048 = 10240 work items
    if (g >= 5*2048) return;
    int mat  = g >> 11;
    int rem  = g & 2047;
    int f    = rem >> 6;                      // 0..31 = nt*4+kt
    int lane = rem & 63;
    int nt = f >> 2, kt = f & 3;
    const float* Ws[5] = {W0,W1,W2,W3,W4};
    const float* src = Ws[mat] + (nt*16 + (lane & 15))*HH + kt*32 + (lane>>4)*8;
    f4 a0 = *(const f4*)&src[0];
    f4 a1 = *(const f4*)&src[4];
    float av[8] = {a0.x,a0.y,a0.z,a0.w,a1.x,a1.y,a1.z,a1.w};
    bf16x8 hv, lv;
    #pragma unroll
    for (int j = 0; j < 8; ++j) { short hh, ll; split_bf16(av[j], hh, ll); hv[j]=hh; lv[j]=ll; }
    size_t o = ((size_t)(mat*32 + f)*64 + lane);
    ((bf16x8*)WFH)[o] = hv;
    ((bf16x8*)WFL)[o] = lv;
}

// ---------------------------------------------------------------------------
// K1: Uh/Vh/Ah/Bh = h @ W{U,V,A,B}^T + b via split-bf16 MFMA.
// 64 blocks (one 16-row j-tile each) x 4 waves (one weight matrix each).
// ---------------------------------------------------------------------------
__global__ __launch_bounds__(256, 2) void k_lin(
    const float* __restrict__ h,
    const short* __restrict__ WFH, const short* __restrict__ WFL,
    const float* __restrict__ b0, const float* __restrict__ b1,
    const float* __restrict__ b2, const float* __restrict__ b3,
    float* __restrict__ out)     // [4][1024][128] = Uh,Vh,Ah,Bh
{
    const int t = threadIdx.x;
    const int lane = t & 63, w = t >> 6;       // wave = matrix select
    const int jt = blockIdx.x;                 // 0..63
    const int m = lane & 15, quad = lane >> 4, nl = m;

    bf16x8 Ahi[4], Alo[4];
    const float* arow = h + (jt*16 + m)*HH + quad*8;
    #pragma unroll
    for (int kt = 0; kt < 4; ++kt) {
        f4 a0 = *(const f4*)&arow[kt*32];
        f4 a1 = *(const f4*)&arow[kt*32 + 4];
        float av[8] = {a0.x,a0.y,a0.z,a0.w,a1.x,a1.y,a1.z,a1.w};
        bf16x8 hv, lv;
        #pragma unroll
        for (int j = 0; j < 8; ++j) { short hh,ll; split_bf16(av[j],hh,ll); hv[j]=hh; lv[j]=ll; }
        Ahi[kt]=hv; Alo[kt]=lv;
    }
    const bf16x8* BH = (const bf16x8*)WFH + (size_t)w*32*64;
    const bf16x8* BL = (const bf16x8*)WFL + (size_t)w*32*64;

    f32x4 acc[8];
    #pragma unroll
    for (int nt = 0; nt < 8; ++nt) acc[nt] = (f32x4){0.f,0.f,0.f,0.f};
    #pragma unroll
    for (int nt = 0; nt < 8; ++nt)
        #pragma unroll
        for (int kt = 0; kt < 4; ++kt) {
            bf16x8 bh = BH[(nt*4+kt)*64 + lane];
            bf16x8 bl = BL[(nt*4+kt)*64 + lane];
            acc[nt] = mfma16(Ahi[kt], bh, acc[nt]);
            acc[nt] = mfma16(Alo[kt], bh, acc[nt]);
            acc[nt] = mfma16(Ahi[kt], bl, acc[nt]);
        }

    const float* bias = (w==0)?b0:(w==1)?b1:(w==2)?b2:b3;
    float* o = out + (size_t)w*(NROWS*HH);
    #pragma unroll
    for (int nt = 0; nt < 8; ++nt) {
        const int n = nt*16 + nl;
        const float bv = bias[n];
        #pragma unroll
        for (int r = 0; r < 4; ++r) {
            const int j = jt*16 + quad*4 + r;   // C/D: col=lane&15, row=quad*4+r
            o[j*HH + n] = acc[nt][r] + bv;
        }
    }
}

// ---------------------------------------------------------------------------
// K2 v3: per (b,i): Ce GEMM (256j x 128n, K=128) via split-bf16 MFMA, fused
// e_new epilogue (store, sigmoid gating, agg_S, agg_A, BN channel sums).
// 1024 blocks x 4 waves; wave w owns j-tiles {4w..4w+3}. A-frags load
// straight from global e (k-contiguous, read-once); B-frags from L2-hot
// fragment arrays. No LDS tiles -> no spill, per-thread ~180 VGPR.
// ---------------------------------------------------------------------------
__global__ __launch_bounds__(256, 2) void k_edge(
    const float* __restrict__ e, const int* __restrict__ A, const int* __restrict__ S,
    const short* __restrict__ WFH, const short* __restrict__ WFL,
    const float* __restrict__ bC,
    const float* __restrict__ Ahw, const float* __restrict__ Bhw,
    const float* __restrict__ Vhw,
    float* __restrict__ eout, float* __restrict__ aggS, float* __restrict__ aggA,
    float* __restrict__ sums)
{
    __shared__ float s_aggS[HH], s_aggA[HH], s_sum[HH], s_ssq[HH];
    const int t = threadIdx.x;
    const int bi = blockIdx.x, b = bi >> 8;
    const int lane = t & 63, w = t >> 6;
    const int nl = lane & 15, quad = lane >> 4;
    if (t < HH) { s_aggS[t]=0.f; s_aggA[t]=0.f; s_sum[t]=0.f; s_ssq[t]=0.f; }
    __syncthreads();

    float bcv[8], bhv[8];
    #pragma unroll
    for (int nt = 0; nt < 8; ++nt) {
        bcv[nt] = bC[nt*16 + nl];
        bhv[nt] = Bhw[bi*HH + nt*16 + nl];      // Bh[b,i,n]
    }
    float sm[8], sq[8], aS[8], aA[8];
    #pragma unroll
    for (int nt = 0; nt < 8; ++nt) { sm[nt]=0.f; sq[nt]=0.f; aS[nt]=0.f; aA[nt]=0.f; }

    const bf16x8* BH = (const bf16x8*)WFH + (size_t)4*32*64;   // mat 4 = WC
    const bf16x8* BL = (const bf16x8*)WFL + (size_t)4*32*64;

    for (int jt = 0; jt < 4; ++jt) {
        const int jtg = w*4 + jt;
        // ---- A fragments straight from global e ----
        bf16x8 Ahi[4], Alo[4];
        const float* arow = e + ((size_t)bi*VV + jtg*16 + nl)*HH + quad*8;
        #pragma unroll
        for (int kt = 0; kt < 4; ++kt) {
            f4 a0 = *(const f4*)&arow[kt*32];
            f4 a1 = *(const f4*)&arow[kt*32 + 4];
            float av[8] = {a0.x,a0.y,a0.z,a0.w,a1.x,a1.y,a1.z,a1.w};
            bf16x8 hv, lv;
            #pragma unroll
            for (int j = 0; j < 8; ++j) { short hh,ll; split_bf16(av[j],hh,ll); hv[j]=hh; lv[j]=ll; }
            Ahi[kt]=hv; Alo[kt]=lv;
        }
        // ---- MFMA: 8 n-tiles x 4 k-tiles x 3 (hi*hi, lo*hi, hi*lo) ----
        f32x4 acc[8];
        #pragma unroll
        for (int nt = 0; nt < 8; ++nt) acc[nt] = (f32x4){0.f,0.f,0.f,0.f};
        #pragma unroll
        for (int nt = 0; nt < 8; ++nt)
            #pragma unroll
            for (int kt = 0; kt < 4; ++kt) {
                bf16x8 bh = BH[(nt*4+kt)*64 + lane];
                bf16x8 bl = BL[(nt*4+kt)*64 + lane];
                acc[nt] = mfma16(Ahi[kt], bh, acc[nt]);
                acc[nt] = mfma16(Alo[kt], bh, acc[nt]);
                acc[nt] = mfma16(Ahi[kt], bl, acc[nt]);
            }
        // ---- epilogue: e_new = acc + bC + Bh[i] + Ah[j]; store; stats ----
        const int j0 = jtg*16 + quad*4;
        #pragma unroll
        for (int r = 0; r < 4; ++r) {
            const int j = j0 + r;
            const int Sij = S[bi*VV + j];
            const int Aij = A[bi*VV + j];
            const float* ahp = Ahw + ((size_t)b*VV + j)*HH;
            const float* vhp = Vhw + ((size_t)b*VV + j)*HH;
            float* eo = eout + ((size_t)bi*VV + j)*HH;
            #pragma unroll
            for (int nt = 0; nt < 8; ++nt) {
                const int n = nt*16 + nl;
                float env = acc[nt][r] + bcv[nt] + bhv[nt] + ahp[n];
                eo[n] = env;
                float vh = vhp[n];
                sm[nt] += env;
                sq[nt] += env*env;
                if (!Aij) aA[nt] += vh;
                if (!Sij) aS[nt] += vh * sigm(env);
            }
        }
    }
    // ---- reduce quads (lanes xor 16,32), then block reduce via LDS ----
    #pragma unroll
    for (int nt = 0; nt < 8; ++nt) {
        float v;
        v = sm[nt]; v += __shfl_xor(v,16,64); v += __shfl_xor(v,32,64); sm[nt]=v;
        v = sq[nt]; v += __shfl_xor(v,16,64); v += __shfl_xor(v,32,64); sq[nt]=v;
        v = aS[nt]; v += __shfl_xor(v,16,64); v += __shfl_xor(v,32,64); aS[nt]=v;
        v = aA[nt]; v += __shfl_xor(v,16,64); v += __shfl_xor(v,32,64); aA[nt]=v;
    }
    if (quad == 0) {
        #pragma unroll
        for (int nt = 0; nt < 8; ++nt) {
            const int n = nt*16 + nl;
            atomicAdd(&s_sum[n],  sm[nt]);
            atomicAdd(&s_ssq[n],  sq[nt]);
            atomicAdd(&s_aggS[n], aS[nt]);
            atomicAdd(&s_aggA[n], aA[nt]);
        }
    }
    __syncthreads();
    if (t < HH) {
        aggS[bi*HH + t] = s_aggS[t];
        aggA[bi*HH + t] = s_aggA[t];
        atomicAdd(&sums[t],      s_sum[t]);
        atomicAdd(&sums[HH + t], s_ssq[t]);
    }
}

// ---------------------------------------------------------------------------
// K3a: h_new = Uh + aggS + aggA ; accumulate h channel sums
// ---------------------------------------------------------------------------
__global__ __launch_bounds__(256) void k_hnew(
    const float* __restrict__ Uh, const float* __restrict__ aggS,
    const float* __restrict__ aggA, float* __restrict__ h_new,
    float* __restrict__ sums)
{
    __shared__ float ssm[HH], ssq[HH];
    const int tid = threadIdx.x;
    if (tid < 128) { ssm[tid]=0.f; ssq[tid]=0.f; }
    __syncthreads();
    int gid = blockIdx.x*256 + tid;
    f4 u = *(const f4*)&Uh[gid*4];
    f4 s = *(const f4*)&aggS[gid*4];
    f4 a = *(const f4*)&aggA[gid*4];
    float v0=u.x+s.x+a.x, v1=u.y+s.y+a.y, v2=u.z+s.z+a.z, v3=u.w+s.w+a.w;
    *(f4*)&h_new[gid*4] = make_float4(v0,v1,v2,v3);
    int n0 = (gid*4) & 127;
    atomicAdd(&ssm[n0+0], v0); atomicAdd(&ssq[n0+0], v0*v0);
    atomicAdd(&ssm[n0+1], v1); atomicAdd(&ssq[n0+1], v1*v1);
    atomicAdd(&ssm[n0+2], v2); atomicAdd(&ssq[n0+2], v2*v2);
    atomicAdd(&ssm[n0+3], v3); atomicAdd(&ssq[n0+3], v3*v3);
    __syncthreads();
    if (tid < 128) {
        atomicAdd(&sums[256 + tid], ssm[tid]);
        atomicAdd(&sums[384 + tid], ssq[tid]);
    }
}

// ---------------------------------------------------------------------------
// K3b: finalize batchnorm params -> scale/shift per channel
// ---------------------------------------------------------------------------
__global__ void k_stats(const float* __restrict__ sums, float* __restrict__ outs,
                        const float* __restrict__ gamma_e, const float* __restrict__ beta_e,
                        const float* __restrict__ gamma_h, const float* __restrict__ beta_h)
{
    int n = threadIdx.x;   // 128
    float em  = sums[n] * (1.f/(float)NE_CNT);
    float ev  = sums[128+n] * (1.f/(float)NE_CNT) - em*em;
    float esc = rsqrtf(ev + EPSV) * gamma_e[n];
    outs[n]       = esc;
    outs[128 + n] = beta_e[n] - em*esc;
    float hm  = sums[256+n] * (1.f/1024.f);
    float hv  = sums[384+n] * (1.f/1024.f) - hm*hm;
    float hsc = rsqrtf(hv + EPSV) * gamma_h[n];
    outs[256 + n] = hsc;
    outs[384 + n] = beta_h[n] - hm*hsc;
}

// ---------------------------------------------------------------------------
// K4h: h_out = h_in + relu(bn(h_new))
// ---------------------------------------------------------------------------
__global__ __launch_bounds__(256) void k_hout(
    const float* __restrict__ h_in, const float* __restrict__ h_new,
    const float* __restrict__ outs, float* __restrict__ hout)
{
    int gid = blockIdx.x*256 + threadIdx.x;
    int n0 = (gid*4) & 127;
    f4 x  = *(const f4*)&h_new[gid*4];
    f4 hi = *(const f4*)&h_in[gid*4];
    f4 sc = *(const f4*)&outs[256 + n0];
    f4 sh = *(const f4*)&outs[384 + n0];
    f4 y;
    y.x = fmaxf(x.x*sc.x + sh.x, 0.f) + hi.x;
    y.y = fmaxf(x.y*sc.y + sh.y, 0.f) + hi.y;
    y.z = fmaxf(x.z*sc.z + sh.z, 0.f) + hi.z;
    y.w = fmaxf(x.w*sc.w + sh.w, 0.f) + hi.w;
    *(f4*)&hout[gid*4] = y;
}

// ---------------------------------------------------------------------------
// K4e: e_out = e_in + relu(bn(e_new))   (e_new lives in-place in d_out)
// ---------------------------------------------------------------------------
__global__ __launch_bounds__(256) void k_eout(
    const float* __restrict__ e_in, const float* __restrict__ outs,
    float* __restrict__ eio)
{
    size_t gid = (size_t)blockIdx.x*256 + threadIdx.x;
    int n0 = ((int)(gid & 31)) << 2;
    f4 x  = *(const f4*)&eio[gid*4];
    f4 ei = *(const f4*)&e_in[gid*4];
    f4 sc = *(const f4*)&outs[n0];
    f4 sh = *(const f4*)&outs[128 + n0];
    f4 y;
    y.x = fmaxf(x.x*sc.x + sh.x, 0.f) + ei.x;
    y.y = fmaxf(x.y*sc.y + sh.y, 0.f) + ei.y;
    y.z = fmaxf(x.z*sc.z + sh.z, 0.f) + ei.z;
    y.w = fmaxf(x.w*sc.w + sh.w, 0.f) + ei.w;
    *(f4*)&eio[gid*4] = y;
}

// ---------------------------------------------------------------------------
extern "C" void kernel_launch(void* const* d_in, const int* in_sizes, int n_in,
                              void* d_out, int out_size, void* d_ws, size_t ws_size,
                              hipStream_t stream)
{
    (void)in_sizes; (void)n_in; (void)out_size; (void)ws_size;
    const float* h   = (const float*)d_in[0];
    const float* e   = (const float*)d_in[1];
    const int*   A   = (const int*)d_in[2];
    const int*   S   = (const int*)d_in[3];
    const float* WU  = (const float*)d_in[4];   const float* bU = (const float*)d_in[5];
    const float* WV  = (const float*)d_in[6];   const float* bV = (const float*)d_in[7];
    const float* WA_ = (const float*)d_in[8];   const float* bA = (const float*)d_in[9];
    const float* WB_ = (const float*)d_in[10];  const float* bB = (const float*)d_in[11];
    const float* WC_ = (const float*)d_in[12];  const float* bC = (const float*)d_in[13];
    const float* gamma_h = (const float*)d_in[14]; const float* beta_h = (const float*)d_in[15];
    const float* gamma_e = (const float*)d_in[16]; const float* beta_e = (const float*)d_in[17];

    float* ws    = (float*)d_ws;
    float* Uh    = ws;                   // [4][1024][128] : Uh,Vh,Ah,Bh
    float* Vh    = ws + 131072;
    float* Ahw   = ws + 262144;
    float* Bhw   = ws + 393216;
    float* aggS  = ws + 524288;
    float* aggA  = ws + 655360;
    float* h_new = ws + 786432;          // 131072 floats
    float* sums  = ws + 917504;          // 512: e_sum, e_ssq, h_sum, h_ssq
    float* outs  = ws + 918016;          // 512: e_scale, e_shift, h_scale, h_shift
    // Weight-fragment arrays alias the h_new region (h_new is only written by
    // k_hnew, after k_lin/k_edge are done with the fragments). 81920 floats
    // needed <= 131072 available.
    short* WFH = (short*)(ws + 786432);           // 5*32*64*8 shorts = 40960 floats
    short* WFL = (short*)(ws + 786432 + 40960);

    float* hout = (float*)d_out;
    float* eout = (float*)d_out + NROWS*HH;       // e_new then e_out, in place

    hipMemsetAsync(sums, 0, 512*sizeof(float), stream);
    k_prep <<<40,    256, 0, stream>>>(WU, WV, WA_, WB_, WC_, WFH, WFL);
    k_lin  <<<64,    256, 0, stream>>>(h, WFH, WFL, bU, bV, bA, bB, Uh);
    k_edge <<<1024,  256, 0, stream>>>(e, A, S, WFH, WFL, bC, Ahw, Bhw, Vh,
                                       eout, aggS, aggA, sums);
    k_hnew <<<128,   256, 0, stream>>>(Uh, aggS, aggA, h_new, sums);
    k_stats<<<1,     128, 0, stream>>>(sums, outs, gamma_e, beta_e, gamma_h, beta_h);
    k_hout <<<128,   256, 0, stream>>>(h, h_new, outs, hout);
    k_eout <<<32768, 256, 0, stream>>>(e, outs, eout);
}